// Round 7
// baseline (84.080 us; speedup 1.0000x reference)
//
#include <hip/hip_runtime.h>
#include <hip/hip_bf16.h>
#include <cstdint>

#define GLOBAL_AS __attribute__((address_space(1)))
#define LDS_AS    __attribute__((address_space(3)))

typedef short s8v  __attribute__((ext_vector_type(8)));
typedef float f4v  __attribute__((ext_vector_type(4)));
typedef unsigned short u8s __attribute__((ext_vector_type(8)));

#define NEGV (-1e7f)

__device__ __forceinline__ void gload_lds16(const void* g, void* l) {
  __builtin_amdgcn_global_load_lds((const GLOBAL_AS uint32_t*)g,
                                   (LDS_AS uint32_t*)l, 16, 0, 0);
}

__device__ __forceinline__ unsigned short f2bf(float f) {
  union { float f; uint32_t u; } v; v.f = f;
  uint32_t u = v.u;
  u += 0x7fffu + ((u >> 16) & 1u);
  return (unsigned short)(u >> 16);
}

// ------------- convert + transpose W1 (K x N f32) -> W1T (N x K bf16) -------------
__global__ __launch_bounds__(256) void cvt_w1t(const float* __restrict__ w1,
                                               unsigned short* __restrict__ w1t) {
  __shared__ float tile[32][33];
  int bx = blockIdx.x & 31;   // n-tile
  int by = blockIdx.x >> 5;   // k-tile
  int tx = threadIdx.x & 31;
  int ty = threadIdx.x >> 5;  // 0..7
#pragma unroll
  for (int j = 0; j < 4; ++j) {
    int kk = ty + j * 8;
    tile[kk][tx] = w1[(size_t)(by * 32 + kk) * 1024 + bx * 32 + tx];
  }
  __syncthreads();
#pragma unroll
  for (int j = 0; j < 4; ++j) {
    int nn = ty + j * 8;
    w1t[(size_t)(bx * 32 + nn) * 1024 + by * 32 + tx] = f2bf(tile[tx][nn]);
  }
}

// ---------------- fused GEMM: h = relu(bert*W1 + b1); partial logits ----------------
// 256x256 tile, BK=64, 8 waves (2M x 4N). R6 change: A (bert_out, f32) is
// reg-staged WITH IN-FLIGHT f32->bf16 CONVERSION (T14 split: ph1 issues 8x
// float4 loads for tile t+1; ph3 converts + ds_write_b128 into the SAME
// swizzled bf16 LDS layout). cvt_a kernel eliminated (-96 MB HBM traffic).
// B stays global_load_lds. Per tile: vmcnt(0) [only B's 4 loads outstanding;
// A regs drained by cvt data-dep] + lgkmcnt(0) at ph4 only. Read side is
// byte-identical to R4/R5 (absmax 0.0, bank conflicts 0).
// Epilogue: atomic-free per-block coalesced store (R5 fix, WRITE 768 KB).
__global__ __launch_bounds__(512, 2) void gemm_fused(
    const float* __restrict__ A32,            // [16384][1024] f32 (bert_out)
    const unsigned short* __restrict__ Bbf,   // [1024][1024] bf16 (W1^T)
    const float* __restrict__ b1,
    const float* __restrict__ W2,             // [1024][3] f32
    float* __restrict__ partials)             // [4][16384][3] f32
{
  __shared__ __align__(16) char lds[131072];  // 2 bufs x (32KB A + 32KB B)

  // bijective XCD swizzle: 256 wgs, 8 XCDs, 32 per XCD
  int bid = blockIdx.x;
  int wid = (bid & 7) * 32 + (bid >> 3);
  int mt = wid >> 2;   // 0..63
  int nt = wid & 3;    // 0..3

  int tid  = threadIdx.x;
  int lane = tid & 63;
  int wv   = tid >> 6;  // 0..7
  int wr   = wv >> 2;   // wave row (0..1): rows wr*128..+127
  int wc   = wv & 3;    // wave col (0..3): cols wc*64..+63

  int laneq = lane & 15;
  int klo   = (lane >> 4) << 4;
  int sw    = (laneq & 7) << 4;
  int x0    = klo ^ sw;
  int x1    = (64 + klo) ^ sw;

  const size_t arow0 = (size_t)mt * 256;
  const size_t brow0 = (size_t)nt * 256;

  // staging source col (bf16-byte units, pre-swizzled); element idx = scol>>1
  int scol = ((lane & 7) * 16) ^ ((lane >> 3) << 4);
  const float* gA32 = A32 + (arow0 + (size_t)wv * 16 + (lane >> 3)) * 1024 + (scol >> 1);
  const unsigned short* gB = Bbf + (brow0 + (lane >> 3)) * 1024 + (scol >> 1)
                                 + (size_t)wv * 16 * 1024;

  f4v acc[8][4];
#pragma unroll
  for (int m = 0; m < 8; ++m)
#pragma unroll
    for (int n = 0; n < 4; ++n)
      acc[m][n] = f4v{0.f, 0.f, 0.f, 0.f};

  s8v a_frag[4][2];
  s8v b_frag[2][2][2];
  float4 areg[8];   // tile t+1's A elements (2 row-halves x 2 rows x 8 k)

  // issue 8x float4 global loads for tile tt (rows r0,r0+8 per half)
  auto A_LOAD = [&](int tt) {
    const float* base = gA32 + tt * 64;
#pragma unroll
    for (int rh = 0; rh < 2; ++rh) {
      const float* p = base + (size_t)rh * 128 * 1024;
      areg[rh * 4 + 0] = *(const float4*)(p);
      areg[rh * 4 + 1] = *(const float4*)(p + 4);
      areg[rh * 4 + 2] = *(const float4*)(p + 8 * 1024);
      areg[rh * 4 + 3] = *(const float4*)(p + 8 * 1024 + 4);
    }
  };
  // convert + ds_write tile tt's A into buf tt&1 (same linear layout gload_lds used)
  auto A_WRITE = [&](int tt) {
    int buf = tt & 1;
#pragma unroll
    for (int rh = 0; rh < 2; ++rh) {
      int dst = (buf << 16) | (rh << 14) | (wv << 11);
#pragma unroll
      for (int rr = 0; rr < 2; ++rr) {
        float4 lo = areg[rh * 4 + rr * 2 + 0];
        float4 hi = areg[rh * 4 + rr * 2 + 1];
        u8s o;
        o[0] = f2bf(lo.x); o[1] = f2bf(lo.y); o[2] = f2bf(lo.z); o[3] = f2bf(lo.w);
        o[4] = f2bf(hi.x); o[5] = f2bf(hi.y); o[6] = f2bf(hi.z); o[7] = f2bf(hi.w);
        *(u8s*)(lds + dst + rr * 1024 + lane * 16) = o;
      }
    }
  };
  // B: both halves of tile tt via global_load_lds (4 loads/thread)
  auto STAGE_B = [&](int tt) {
    const unsigned short* g = gB + tt * 64;
#pragma unroll
    for (int rh = 0; rh < 2; ++rh) {
      int dst = ((tt & 1) << 16) | (1 << 15) | (rh << 14) | (wv << 11);
      const unsigned short* p = g + (size_t)rh * 128 * 1024;
      gload_lds16(p,            lds + dst);
      gload_lds16(p + 8 * 1024, lds + dst + 1024);
    }
  };

  auto READ_A = [&](int buf, int mq) {
    const char* p = lds + (buf << 16) + (wr << 14) + laneq * 128 + mq * 8192;
#pragma unroll
    for (int m = 0; m < 4; ++m) {
      a_frag[m][0] = *(const s8v*)(p + m * 2048 + x0);
      a_frag[m][1] = *(const s8v*)(p + m * 2048 + x1);
    }
  };
  auto READ_B = [&](int buf, int np) {
    const char* p = lds + (buf << 16) + 32768 + ((wc >> 1) << 14)
                        + ((wc & 1) * 64 + laneq) * 128 + np * 4096;
#pragma unroll
    for (int n2 = 0; n2 < 2; ++n2) {
      b_frag[np][n2][0] = *(const s8v*)(p + n2 * 2048 + x0);
      b_frag[np][n2][1] = *(const s8v*)(p + n2 * 2048 + x1);
    }
  };
  auto MFMA_Q = [&](int mq, int np) {
    __builtin_amdgcn_s_setprio(1);
#pragma unroll
    for (int m = 0; m < 4; ++m)
#pragma unroll
      for (int n2 = 0; n2 < 2; ++n2) {
        acc[mq*4+m][np*2+n2] = __builtin_amdgcn_mfma_f32_16x16x32_bf16(
            a_frag[m][0], b_frag[np][n2][0], acc[mq*4+m][np*2+n2], 0, 0, 0);
        acc[mq*4+m][np*2+n2] = __builtin_amdgcn_mfma_f32_16x16x32_bf16(
            a_frag[m][1], b_frag[np][n2][1], acc[mq*4+m][np*2+n2], 0, 0, 0);
      }
    __builtin_amdgcn_s_setprio(0);
  };

#define BAR  __builtin_amdgcn_s_barrier()
#define SB0  __builtin_amdgcn_sched_barrier(0)
#define VM0  asm volatile("s_waitcnt vmcnt(0)" ::: "memory")
#define LK0  asm volatile("s_waitcnt lgkmcnt(0)" ::: "memory")

  // prologue: fully stage tile 0
  A_LOAD(0);
  STAGE_B(0);
  A_WRITE(0);           // compiler inserts the vmcnt wait for areg deps
  VM0; LK0; SB0;
  BAR;

  for (int t = 0; t < 16; ++t) {
    int c = t & 1;
    bool pf = (t < 15);
    // ph1: issue next A loads; read quadrant frags
    if (pf) A_LOAD(t + 1);
    READ_A(c, 0); READ_B(c, 0);
    BAR; SB0; MFMA_Q(0, 0); SB0; BAR;
    // ph2: stage next B (direct-to-LDS, stays in flight across barriers)
    if (pf) STAGE_B(t + 1);
    READ_B(c, 1);
    BAR; SB0; MFMA_Q(0, 1); SB0; BAR;
    // ph3: convert + write next A into other buffer
    READ_A(c, 1);
    if (pf) A_WRITE(t + 1);
    BAR; SB0; MFMA_Q(1, 1); SB0; BAR;
    // ph4: publish next tile (B landed, A writes visible)
    VM0; LK0; SB0;
    BAR; SB0; MFMA_Q(1, 0); SB0; BAR;
  }

#undef BAR
#undef SB0
#undef VM0
#undef LK0

  // ---- epilogue: h = relu(acc + b1); p = h*W2; shfl-reduce; LDS-reduce over wc;
  //      ONE coalesced store per block (no atomics — R5 fix) ----
  float b1v[4];
  float w2v[4][3];
#pragma unroll
  for (int n = 0; n < 4; ++n) {
    int gc = nt * 256 + wc * 64 + n * 16 + laneq;
    b1v[n] = b1[gc];
    w2v[n][0] = W2[gc * 3 + 0];
    w2v[n][1] = W2[gc * 3 + 1];
    w2v[n][2] = W2[gc * 3 + 2];
  }

  float* red = (float*)lds;   // [4 wc][256 rows][3] f32 = 12 KB (K-loop LDS dead)
#pragma unroll
  for (int m = 0; m < 8; ++m) {
#pragma unroll
    for (int q = 0; q < 4; ++q) {
      float p0 = 0.f, p1 = 0.f, p2 = 0.f;
#pragma unroll
      for (int n = 0; n < 4; ++n) {
        float h = acc[m][n][q] + b1v[n];
        h = fmaxf(h, 0.f);
        p0 += h * w2v[n][0];
        p1 += h * w2v[n][1];
        p2 += h * w2v[n][2];
      }
#pragma unroll
      for (int s = 1; s < 16; s <<= 1) {
        p0 += __shfl_xor(p0, s, 64);
        p1 += __shfl_xor(p1, s, 64);
        p2 += __shfl_xor(p2, s, 64);
      }
      if ((lane & 15) == 0) {
        int row = wr * 128 + m * 16 + (lane >> 4) * 4 + q;   // 0..255
        red[(wc * 256 + row) * 3 + 0] = p0;
        red[(wc * 256 + row) * 3 + 1] = p1;
        red[(wc * 256 + row) * 3 + 2] = p2;
      }
    }
  }
  __syncthreads();
  if (tid < 256) {
    float s0 = 0.f, s1 = 0.f, s2 = 0.f;
#pragma unroll
    for (int w = 0; w < 4; ++w) {
      s0 += red[(w * 256 + tid) * 3 + 0];
      s1 += red[(w * 256 + tid) * 3 + 1];
      s2 += red[(w * 256 + tid) * 3 + 2];
    }
    size_t o = ((size_t)nt * 16384 + (size_t)mt * 256 + tid) * 3;
    partials[o + 0] = s0;
    partials[o + 1] = s1;
    partials[o + 2] = s2;
  }
}

// ---------------- finalize: sum partials, log-softmax, gather, logsumexp ----------------
__device__ __forceinline__ float blockReduceSum(float v, float* red, int t) {
#pragma unroll
  for (int s = 32; s >= 1; s >>= 1) v += __shfl_xor(v, s, 64);
  __syncthreads();
  if ((t & 63) == 0) red[t >> 6] = v;
  __syncthreads();
  return red[0] + red[1] + red[2] + red[3];
}

__global__ __launch_bounds__(256) void finalize(
    const float* __restrict__ partials, // [4][16384][3]
    const float* __restrict__ b2,       // [3]
    const int* __restrict__ seq_mask,   // [32][512]
    const int* __restrict__ ans,        // [32][8][512]
    const int* __restrict__ span,       // [32][512]
    const int* __restrict__ isbio,      // [32]
    float* __restrict__ out)            // [32]
{
  int b = blockIdx.x;
  int t = threadIdx.x;
  __shared__ float lp[512][3];
  __shared__ float red[4];
  __shared__ float seq_ll[9];
  __shared__ int preg;

  float b20 = b2[0], b21 = b2[1], b22 = b2[2];
  const int NP = 16384 * 3;

  for (int l = t; l < 512; l += 256) {
    int gi = b * 512 + l;
    float x0 = b20, x1 = b21, x2 = b22;
#pragma unroll
    for (int w = 0; w < 4; ++w) {
      x0 += partials[w * NP + gi * 3 + 0];
      x1 += partials[w * NP + gi * 3 + 1];
      x2 += partials[w * NP + gi * 3 + 2];
    }
    float mx = fmaxf(x0, fmaxf(x1, x2));
    float lse = mx + logf(expf(x0 - mx) + expf(x1 - mx) + expf(x2 - mx));
    float msk = (float)seq_mask[gi];
    lp[l][0] = (x0 - lse) * msk;
    lp[l][1] = (x1 - lse) * msk;
    lp[l][2] = (x2 - lse) * msk;
  }
  __syncthreads();

  // is_pregen = sum(ans * seq_mask) > 0
  float s = 0.f;
  for (int i = t; i < 8 * 512; i += 256) {
    int m = i >> 9, l = i & 511;
    s += (float)(ans[(b * 8 + m) * 512 + l] * seq_mask[b * 512 + l]);
  }
  s = blockReduceSum(s, red, t);
  if (t == 0) preg = (s > 0.f) ? 1 : 0;
  __syncthreads();
  int ip = preg;

  for (int m = 0; m < 9; ++m) {
    float sll = 0.f, sidx = 0.f;
    for (int l = t; l < 512; l += 256) {
      int idx;
      if (m < 8) idx = ans[(b * 8 + m) * 512 + l] * seq_mask[b * 512 + l];
      else       idx = span[b * 512 + l] * (1 - ip);
      sll  += lp[l][idx];
      sidx += (float)idx;
    }
    sll  = blockReduceSum(sll, red, t);
    sidx = blockReduceSum(sidx, red, t);
    if (t == 0) seq_ll[m] = (sidx > 0.f) ? sll : NEGV;
  }

  if (t == 0) {
    float mx = seq_ll[0];
#pragma unroll
    for (int m = 1; m < 9; ++m) mx = fmaxf(mx, seq_ll[m]);
    float sum = 0.f;
#pragma unroll
    for (int m = 0; m < 9; ++m) sum += expf(seq_ll[m] - mx);
    float lml = mx + logf(sum);
    out[b] = isbio[b] ? lml : NEGV;
  }
}

extern "C" void kernel_launch(void* const* d_in, const int* in_sizes, int n_in,
                              void* d_out, int out_size, void* d_ws, size_t ws_size,
                              hipStream_t stream) {
  const float* bert     = (const float*)d_in[0];
  const int*   seq_mask = (const int*)d_in[1];
  // d_in[2] wordpiece_mask: unused
  // d_in[3] answer_as_text_to_disjoint_bios: unused
  const int*   ans      = (const int*)d_in[4];
  const int*   span     = (const int*)d_in[5];
  const int*   isbio    = (const int*)d_in[6];
  const float* W1       = (const float*)d_in[7];
  const float* b1       = (const float*)d_in[8];
  const float* W2       = (const float*)d_in[9];
  const float* b2       = (const float*)d_in[10];
  float* out = (float*)d_out;

  char* ws = (char*)d_ws;
  float* partials     = (float*)ws;                        // 768 KB, fully written each call
  unsigned short* W1T = (unsigned short*)(ws + (1 << 20)); // 2 MB

  cvt_w1t<<<1024, 256, 0, stream>>>(W1, W1T);
  gemm_fused<<<256, 512, 0, stream>>>(bert, W1T, b1, W2, partials);
  finalize<<<32, 256, 0, stream>>>(partials, b2, seq_mask, ans, span, isbio, out);
}

// Round 8
// 83.065 us; speedup vs baseline: 1.0122x; 1.0122x over previous
//
#include <hip/hip_runtime.h>
#include <hip/hip_bf16.h>
#include <cstdint>

#define GLOBAL_AS __attribute__((address_space(1)))
#define LDS_AS    __attribute__((address_space(3)))

typedef short s8v  __attribute__((ext_vector_type(8)));
typedef float f4v  __attribute__((ext_vector_type(4)));
typedef unsigned short u8s __attribute__((ext_vector_type(8)));

#define NEGV (-1e7f)

__device__ __forceinline__ void gload_lds16(const void* g, void* l) {
  __builtin_amdgcn_global_load_lds((const GLOBAL_AS uint32_t*)g,
                                   (LDS_AS uint32_t*)l, 16, 0, 0);
}

__device__ __forceinline__ unsigned short f2bf(float f) {
  union { float f; uint32_t u; } v; v.f = f;
  uint32_t u = v.u;
  u += 0x7fffu + ((u >> 16) & 1u);
  return (unsigned short)(u >> 16);
}

// ------------- convert + transpose W1 (K x N f32) -> W1T (N x K bf16) -------------
__global__ __launch_bounds__(256) void cvt_w1t(const float* __restrict__ w1,
                                               unsigned short* __restrict__ w1t) {
  __shared__ float tile[32][33];
  int bx = blockIdx.x & 31;   // n-tile
  int by = blockIdx.x >> 5;   // k-tile
  int tx = threadIdx.x & 31;
  int ty = threadIdx.x >> 5;  // 0..7
#pragma unroll
  for (int j = 0; j < 4; ++j) {
    int kk = ty + j * 8;
    tile[kk][tx] = w1[(size_t)(by * 32 + kk) * 1024 + bx * 32 + tx];
  }
  __syncthreads();
#pragma unroll
  for (int j = 0; j < 4; ++j) {
    int nn = ty + j * 8;
    w1t[(size_t)(bx * 32 + nn) * 1024 + by * 32 + tx] = f2bf(tile[tx][nn]);
  }
}

// ---------------- fused GEMM: h = relu(bert*W1 + b1); partial logits ----------------
// R8: 128x128 tile, BK=64, 4 waves, LDS 64 KB -> 2 BLOCKS/CU (R7 post-mortem:
// all prior rounds ran 1 block/CU, so every barrier/latency stall was fully
// exposed — co-resident block now hides drains). grid = 128mt x 8nt = 1024.
// A (f32) reg-staged with in-flight f32->bf16 cvt: loads issued top-of-iter,
// cvt+ds_write (SWIZZLED dest, linear source — rule 21 reg-staging variant)
// between the two k-half compute phases; compiler inserts the counted vmcnt
// for the areg data-dep. B via gload_lds (pre-swizzled source, linear dest).
// ONE __syncthreads per tile. Read path byte-identical to verified R2 kernel.
// Epilogue: atomic-free per-block coalesced store into partials[8][16384][3].
__global__ __launch_bounds__(256, 2) void gemm_fused(
    const float* __restrict__ A32,            // [16384][1024] f32 (bert_out)
    const unsigned short* __restrict__ Bbf,   // [1024][1024] bf16 (W1^T)
    const float* __restrict__ b1,
    const float* __restrict__ W2,             // [1024][3] f32
    float* __restrict__ partials)             // [8][16384][3] f32
{
  __shared__ __align__(16) char lds[65536];   // 2 bufs x (16KB A + 16KB B)

  // bijective XCD swizzle: 1024 wgs, 8 XCDs, 128 per XCD
  int bid = blockIdx.x;
  int wid = (bid & 7) * 128 + (bid >> 3);
  int mt = wid >> 3;   // 0..127
  int nt = wid & 7;    // 0..7

  int tid  = threadIdx.x;
  int lane = tid & 63;
  int wv   = tid >> 6;  // 0..3
  int wr   = wv >> 1;   // wave row (0..1): rows wr*64..+63
  int wc   = wv & 1;    // wave col (0..1): cols wc*64..+63

  int laneq = lane & 15;
  int klo   = (lane >> 4) << 4;   // 0,16,32,48

  const size_t arow0 = (size_t)mt * 128;
  const size_t brow0 = (size_t)nt * 128;

  // ---- A reg-staging geometry: thread covers rows arow_l+32p (p=0..3), 8 f32 each
  int arow_l = tid >> 3;               // 0..31
  int acol   = (tid & 7) * 8;          // f32 element col (linear, coalesced)
  const float* gA = A32 + (arow0 + arow_l) * 1024 + acol;
  int adst_col = ((tid & 7) * 16) ^ ((arow_l & 7) << 4);  // swizzled bf16 byte col
                                                           // (row&7 == arow_l&7 since 32p%8==0)
  // ---- B gload_lds geometry (per thread 4 chunks, linear dest, pre-swz source)
  int scb = (lane & 7) * 16;

  f4v acc[4][4];
#pragma unroll
  for (int m = 0; m < 4; ++m)
#pragma unroll
    for (int n = 0; n < 4; ++n)
      acc[m][n] = f4v{0.f, 0.f, 0.f, 0.f};

  float4 areg[4][2];

  auto A_LOAD = [&](int t) {
    const float* p = gA + t * 64;
#pragma unroll
    for (int pq = 0; pq < 4; ++pq) {
      areg[pq][0] = *(const float4*)(p + (size_t)pq * 32 * 1024);
      areg[pq][1] = *(const float4*)(p + (size_t)pq * 32 * 1024 + 4);
    }
  };
  auto A_WRITE = [&](int t) {
    char* base = lds + ((t & 1) << 15);
#pragma unroll
    for (int pq = 0; pq < 4; ++pq) {
      float4 lo = areg[pq][0], hi = areg[pq][1];
      u8s o;
      o[0] = f2bf(lo.x); o[1] = f2bf(lo.y); o[2] = f2bf(lo.z); o[3] = f2bf(lo.w);
      o[4] = f2bf(hi.x); o[5] = f2bf(hi.y); o[6] = f2bf(hi.z); o[7] = f2bf(hi.w);
      *(u8s*)(base + (arow_l + 32 * pq) * 128 + adst_col) = o;
    }
  };
  auto STAGE_B = [&](int t) {
    char* base = lds + ((t & 1) << 15) + 16384;
#pragma unroll
    for (int c = 0; c < 4; ++c) {
      int row = wv * 32 + c * 8 + (lane >> 3);
      int src = scb ^ ((row & 7) << 4);
      gload_lds16(Bbf + (brow0 + row) * 1024 + t * 64 + (src >> 1),
                  base + (wv * 4 + c) * 1024);
    }
  };

  auto COMPUTE_KH = [&](int c, int kh) {
    const char* As = lds + (c << 15);
    const char* Bs = As + 16384;
    int kb = kh * 64 + klo;
    s8v av[4], bv[4];
#pragma unroll
    for (int m = 0; m < 4; ++m) {
      int ra = wr * 64 + m * 16 + laneq;
      av[m] = *(const s8v*)(As + ra * 128 + (kb ^ ((ra & 7) << 4)));
    }
#pragma unroll
    for (int n = 0; n < 4; ++n) {
      int rb = wc * 64 + n * 16 + laneq;
      bv[n] = *(const s8v*)(Bs + rb * 128 + (kb ^ ((rb & 7) << 4)));
    }
    __builtin_amdgcn_s_setprio(1);
#pragma unroll
    for (int m = 0; m < 4; ++m)
#pragma unroll
      for (int n = 0; n < 4; ++n)
        acc[m][n] = __builtin_amdgcn_mfma_f32_16x16x32_bf16(av[m], bv[n], acc[m][n], 0, 0, 0);
    __builtin_amdgcn_s_setprio(0);
  };

  // prologue: fully stage tile 0 (compiler inserts vmcnt for areg dep)
  A_LOAD(0);
  STAGE_B(0);
  A_WRITE(0);
  __syncthreads();

  for (int t = 0; t < 16; ++t) {
    int c = t & 1;
    bool pf = (t < 15);
    if (pf) { A_LOAD(t + 1); STAGE_B(t + 1); }   // 12 vmem in flight over the iter
    COMPUTE_KH(c, 0);
    if (pf) A_WRITE(t + 1);   // to buf 1-c; compiler waits exactly for areg loads
    COMPUTE_KH(c, 1);
    __syncthreads();          // drains vmcnt (B landed) + lgkm (A writes visible)
  }

  // ---- epilogue: h = relu(acc + b1); p = h*W2; shfl-reduce; LDS-reduce over wc;
  //      ONE coalesced store per block (no atomics — R5 fix) ----
  float b1v[4];
  float w2v[4][3];
#pragma unroll
  for (int n = 0; n < 4; ++n) {
    int gc = nt * 128 + wc * 64 + n * 16 + laneq;
    b1v[n] = b1[gc];
    w2v[n][0] = W2[gc * 3 + 0];
    w2v[n][1] = W2[gc * 3 + 1];
    w2v[n][2] = W2[gc * 3 + 2];
  }

  float* red = (float*)lds;   // [2 wc][128 rows][3] f32 = 3 KB (K-loop LDS dead)
#pragma unroll
  for (int m = 0; m < 4; ++m) {
#pragma unroll
    for (int q = 0; q < 4; ++q) {
      float p0 = 0.f, p1 = 0.f, p2 = 0.f;
#pragma unroll
      for (int n = 0; n < 4; ++n) {
        float h = acc[m][n][q] + b1v[n];
        h = fmaxf(h, 0.f);
        p0 += h * w2v[n][0];
        p1 += h * w2v[n][1];
        p2 += h * w2v[n][2];
      }
#pragma unroll
      for (int s = 1; s < 16; s <<= 1) {
        p0 += __shfl_xor(p0, s, 64);
        p1 += __shfl_xor(p1, s, 64);
        p2 += __shfl_xor(p2, s, 64);
      }
      if ((lane & 15) == 0) {
        int row = wr * 64 + m * 16 + (lane >> 4) * 4 + q;   // 0..127
        red[(wc * 128 + row) * 3 + 0] = p0;
        red[(wc * 128 + row) * 3 + 1] = p1;
        red[(wc * 128 + row) * 3 + 2] = p2;
      }
    }
  }
  __syncthreads();
  if (tid < 128) {
    float s0 = 0.f, s1 = 0.f, s2 = 0.f;
#pragma unroll
    for (int w = 0; w < 2; ++w) {
      s0 += red[(w * 128 + tid) * 3 + 0];
      s1 += red[(w * 128 + tid) * 3 + 1];
      s2 += red[(w * 128 + tid) * 3 + 2];
    }
    size_t o = ((size_t)nt * 16384 + (size_t)mt * 128 + tid) * 3;
    partials[o + 0] = s0;
    partials[o + 1] = s1;
    partials[o + 2] = s2;
  }
}

// ---------------- finalize: sum partials, log-softmax, gather, logsumexp ----------------
__device__ __forceinline__ float blockReduceSum(float v, float* red, int t) {
#pragma unroll
  for (int s = 32; s >= 1; s >>= 1) v += __shfl_xor(v, s, 64);
  __syncthreads();
  if ((t & 63) == 0) red[t >> 6] = v;
  __syncthreads();
  return red[0] + red[1] + red[2] + red[3];
}

__global__ __launch_bounds__(256) void finalize(
    const float* __restrict__ partials, // [8][16384][3]
    const float* __restrict__ b2,       // [3]
    const int* __restrict__ seq_mask,   // [32][512]
    const int* __restrict__ ans,        // [32][8][512]
    const int* __restrict__ span,       // [32][512]
    const int* __restrict__ isbio,     // [32]
    float* __restrict__ out)            // [32]
{
  int b = blockIdx.x;
  int t = threadIdx.x;
  __shared__ float lp[512][3];
  __shared__ float red[4];
  __shared__ float seq_ll[9];
  __shared__ int preg;

  float b20 = b2[0], b21 = b2[1], b22 = b2[2];
  const int NP = 16384 * 3;

  for (int l = t; l < 512; l += 256) {
    int gi = b * 512 + l;
    float x0 = b20, x1 = b21, x2 = b22;
#pragma unroll
    for (int w = 0; w < 8; ++w) {
      x0 += partials[w * NP + gi * 3 + 0];
      x1 += partials[w * NP + gi * 3 + 1];
      x2 += partials[w * NP + gi * 3 + 2];
    }
    float mx = fmaxf(x0, fmaxf(x1, x2));
    float lse = mx + logf(expf(x0 - mx) + expf(x1 - mx) + expf(x2 - mx));
    float msk = (float)seq_mask[gi];
    lp[l][0] = (x0 - lse) * msk;
    lp[l][1] = (x1 - lse) * msk;
    lp[l][2] = (x2 - lse) * msk;
  }
  __syncthreads();

  // is_pregen = sum(ans * seq_mask) > 0
  float s = 0.f;
  for (int i = t; i < 8 * 512; i += 256) {
    int m = i >> 9, l = i & 511;
    s += (float)(ans[(b * 8 + m) * 512 + l] * seq_mask[b * 512 + l]);
  }
  s = blockReduceSum(s, red, t);
  if (t == 0) preg = (s > 0.f) ? 1 : 0;
  __syncthreads();
  int ip = preg;

  for (int m = 0; m < 9; ++m) {
    float sll = 0.f, sidx = 0.f;
    for (int l = t; l < 512; l += 256) {
      int idx;
      if (m < 8) idx = ans[(b * 8 + m) * 512 + l] * seq_mask[b * 512 + l];
      else       idx = span[b * 512 + l] * (1 - ip);
      sll  += lp[l][idx];
      sidx += (float)idx;
    }
    sll  = blockReduceSum(sll, red, t);
    sidx = blockReduceSum(sidx, red, t);
    if (t == 0) seq_ll[m] = (sidx > 0.f) ? sll : NEGV;
  }

  if (t == 0) {
    float mx = seq_ll[0];
#pragma unroll
    for (int m = 1; m < 9; ++m) mx = fmaxf(mx, seq_ll[m]);
    float sum = 0.f;
#pragma unroll
    for (int m = 0; m < 9; ++m) sum += expf(seq_ll[m] - mx);
    float lml = mx + logf(sum);
    out[b] = isbio[b] ? lml : NEGV;
  }
}

extern "C" void kernel_launch(void* const* d_in, const int* in_sizes, int n_in,
                              void* d_out, int out_size, void* d_ws, size_t ws_size,
                              hipStream_t stream) {
  const float* bert     = (const float*)d_in[0];
  const int*   seq_mask = (const int*)d_in[1];
  // d_in[2] wordpiece_mask: unused
  // d_in[3] answer_as_text_to_disjoint_bios: unused
  const int*   ans      = (const int*)d_in[4];
  const int*   span     = (const int*)d_in[5];
  const int*   isbio    = (const int*)d_in[6];
  const float* W1       = (const float*)d_in[7];
  const float* b1       = (const float*)d_in[8];
  const float* W2       = (const float*)d_in[9];
  const float* b2       = (const float*)d_in[10];
  float* out = (float*)d_out;

  char* ws = (char*)d_ws;
  float* partials     = (float*)ws;                        // 1.5 MB, fully written each call
  unsigned short* W1T = (unsigned short*)(ws + (1 << 21)); // 2 MB

  cvt_w1t<<<1024, 256, 0, stream>>>(W1, W1T);
  gemm_fused<<<1024, 256, 0, stream>>>(bert, W1T, b1, W2, partials);
  finalize<<<32, 256, 0, stream>>>(partials, b2, seq_mask, ans, span, isbio, out);
}

// Round 9
// 76.563 us; speedup vs baseline: 1.0982x; 1.0849x over previous
//
#include <hip/hip_runtime.h>
#include <hip/hip_bf16.h>
#include <cstdint>

#define GLOBAL_AS __attribute__((address_space(1)))
#define LDS_AS    __attribute__((address_space(3)))

typedef short s8v  __attribute__((ext_vector_type(8)));
typedef float f4v  __attribute__((ext_vector_type(4)));
typedef unsigned short u8s __attribute__((ext_vector_type(8)));

#define NEGV (-1e7f)

__device__ __forceinline__ void gload_lds16(const void* g, void* l) {
  __builtin_amdgcn_global_load_lds((const GLOBAL_AS uint32_t*)g,
                                   (LDS_AS uint32_t*)l, 16, 0, 0);
}

__device__ __forceinline__ unsigned short f2bf(float f) {
  union { float f; uint32_t u; } v; v.f = f;
  uint32_t u = v.u;
  u += 0x7fffu + ((u >> 16) & 1u);
  return (unsigned short)(u >> 16);
}

// ------- combined: bert f32->bf16 (blocks 0..2047) + W1 transpose-cvt (2048..3071) -------
__global__ __launch_bounds__(256) void cvt_all(const float* __restrict__ bert,
                                               unsigned short* __restrict__ abf,
                                               const float* __restrict__ w1,
                                               unsigned short* __restrict__ w1t) {
  __shared__ float tile[32][33];
  if (blockIdx.x < 2048) {
    const int n8 = 16384 * 1024 / 8;
    int i = blockIdx.x * 256 + threadIdx.x;
    for (; i < n8; i += 2048 * 256) {
      float4 a = ((const float4*)bert)[2 * i + 0];
      float4 b = ((const float4*)bert)[2 * i + 1];
      u8s o;
      o[0] = f2bf(a.x); o[1] = f2bf(a.y); o[2] = f2bf(a.z); o[3] = f2bf(a.w);
      o[4] = f2bf(b.x); o[5] = f2bf(b.y); o[6] = f2bf(b.z); o[7] = f2bf(b.w);
      ((u8s*)abf)[i] = o;
    }
  } else {
    int bb = blockIdx.x - 2048;
    int bx = bb & 31;   // n-tile
    int by = bb >> 5;   // k-tile
    int tx = threadIdx.x & 31;
    int ty = threadIdx.x >> 5;  // 0..7
#pragma unroll
    for (int j = 0; j < 4; ++j) {
      int kk = ty + j * 8;
      tile[kk][tx] = w1[(size_t)(by * 32 + kk) * 1024 + bx * 32 + tx];
    }
    __syncthreads();
#pragma unroll
    for (int j = 0; j < 4; ++j) {
      int nn = ty + j * 8;
      w1t[(size_t)(bx * 32 + nn) * 1024 + by * 32 + tx] = f2bf(tile[tx][nn]);
    }
  }
}

// ---------------- fused GEMM: h = relu(A*W1 + b1); partial logits ----------------
// R9 = R6's 42us kernel with ONE change: trailing sched_barrier(0) after each
// MFMA cluster REMOVED. Phase = READS; STAGE; [VM4]; BAR; SB0; MFMA; BAR.
// Next phase's ds_reads/stage may now slide into this phase's MFMA window
// (reads||MFMA overlap, m201-style); the window-top SB0 caps all hoisting at
// BAR1, which is the publish barrier (VM4 precedes it at ph4/ph8), so hoisted
// ops only execute after all waves' reads are issued / stages drained — safe.
// Epilogue: atomic-free per-block coalesced store (R5 fix).
__global__ __launch_bounds__(512, 2) void gemm_fused(
    const unsigned short* __restrict__ Abf,   // [16384][1024] bf16
    const unsigned short* __restrict__ Bbf,   // [1024][1024] bf16 (W1^T)
    const float* __restrict__ b1,
    const float* __restrict__ W2,             // [1024][3] f32
    float* __restrict__ partials)             // [4][16384][3] f32
{
  __shared__ __align__(16) char lds[147456];  // 2x64KB tile bufs + 16KB dummy

  // bijective XCD swizzle: 256 wgs, 8 XCDs, 32 per XCD
  int bid = blockIdx.x;
  int wid = (bid & 7) * 32 + (bid >> 3);
  int mt = wid >> 2;   // 0..63
  int nt = wid & 3;    // 0..3

  int tid  = threadIdx.x;
  int lane = tid & 63;
  int wv   = tid >> 6;  // 0..7
  int wr   = wv >> 2;   // wave row (0..1): rows wr*128..+127
  int wc   = wv & 3;    // wave col (0..3): cols wc*64..+63

  int laneq = lane & 15;
  int klo   = (lane >> 4) << 4;
  int sw    = (laneq & 7) << 4;
  int x0    = klo ^ sw;
  int x1    = (64 + klo) ^ sw;

  const size_t arow0 = (size_t)mt * 256;
  const size_t brow0 = (size_t)nt * 256;

  int scol = ((lane & 7) * 16) ^ ((lane >> 3) << 4);
  const unsigned short* gA = Abf + (arow0 + (lane >> 3)) * 1024 + (scol >> 1)
                                 + (size_t)wv * 16 * 1024;
  const unsigned short* gB = Bbf + (brow0 + (lane >> 3)) * 1024 + (scol >> 1)
                                 + (size_t)wv * 16 * 1024;

  f4v acc[8][4];
#pragma unroll
  for (int m = 0; m < 8; ++m)
#pragma unroll
    for (int n = 0; n < 4; ++n)
      acc[m][n] = f4v{0.f, 0.f, 0.f, 0.f};

  s8v a_frag[4][2];
  s8v b_frag[2][2][2];

  auto STAGE = [&](int ts, int isB, int rh) {
    int ok  = ts < 16;
    int tcl = ok ? ts : 15;
    const unsigned short* g = (isB ? gB : gA) + (size_t)rh * 128 * 1024 + tcl * 64;
    int dst = ok ? (((tcl & 1) << 16) | (isB << 15) | (rh << 14) | (wv << 11))
                 : (131072 + (wv << 11));
    gload_lds16(g,            lds + dst);
    gload_lds16(g + 8 * 1024, lds + dst + 1024);
  };

  auto READ_A = [&](int buf, int mq) {
    const char* p = lds + (buf << 16) + (wr << 14) + laneq * 128 + mq * 8192;
#pragma unroll
    for (int m = 0; m < 4; ++m) {
      a_frag[m][0] = *(const s8v*)(p + m * 2048 + x0);
      a_frag[m][1] = *(const s8v*)(p + m * 2048 + x1);
    }
  };
  auto READ_B = [&](int buf, int np) {
    const char* p = lds + (buf << 16) + 32768 + ((wc >> 1) << 14)
                        + ((wc & 1) * 64 + laneq) * 128 + np * 4096;
#pragma unroll
    for (int n2 = 0; n2 < 2; ++n2) {
      b_frag[np][n2][0] = *(const s8v*)(p + n2 * 2048 + x0);
      b_frag[np][n2][1] = *(const s8v*)(p + n2 * 2048 + x1);
    }
  };
  auto MFMA_Q = [&](int mq, int np) {
    __builtin_amdgcn_s_setprio(1);
#pragma unroll
    for (int m = 0; m < 4; ++m)
#pragma unroll
      for (int n2 = 0; n2 < 2; ++n2) {
        acc[mq*4+m][np*2+n2] = __builtin_amdgcn_mfma_f32_16x16x32_bf16(
            a_frag[m][0], b_frag[np][n2][0], acc[mq*4+m][np*2+n2], 0, 0, 0);
        acc[mq*4+m][np*2+n2] = __builtin_amdgcn_mfma_f32_16x16x32_bf16(
            a_frag[m][1], b_frag[np][n2][1], acc[mq*4+m][np*2+n2], 0, 0, 0);
      }
    __builtin_amdgcn_s_setprio(0);
  };

#define BAR  __builtin_amdgcn_s_barrier()
#define SB0  __builtin_amdgcn_sched_barrier(0)
#define VM4  asm volatile("s_waitcnt vmcnt(4)" ::: "memory")

  // prologue: tile0 all 4 slots + tile1 {B,h0},{A,h0}; drain tile0, keep 2 in flight
  STAGE(0,1,0); STAGE(0,0,0); STAGE(0,0,1); STAGE(0,1,1);
  STAGE(1,1,0); STAGE(1,0,0);
  VM4; BAR; SB0;

  for (int i = 0; i < 8; ++i) {
    int T = 2 * i;
    // ---- tile T (buf 0) ----
    READ_A(0,0); READ_B(0,0); STAGE(T+1,0,1);
    BAR; SB0; MFMA_Q(0,0); BAR;
    READ_B(0,1);             STAGE(T+1,1,1);
    BAR; SB0; MFMA_Q(0,1); BAR;
    READ_A(0,1);             STAGE(T+2,1,0);
    BAR; SB0; MFMA_Q(1,1); BAR;
                             STAGE(T+2,0,0);
    VM4;
    BAR; SB0; MFMA_Q(1,0); BAR;
    // ---- tile T+1 (buf 1) ----
    READ_A(1,0); READ_B(1,0); STAGE(T+2,0,1);
    BAR; SB0; MFMA_Q(0,0); BAR;
    READ_B(1,1);             STAGE(T+2,1,1);
    BAR; SB0; MFMA_Q(0,1); BAR;
    READ_A(1,1);             STAGE(T+3,1,0);
    BAR; SB0; MFMA_Q(1,1); BAR;
                             STAGE(T+3,0,0);
    VM4;
    BAR; SB0; MFMA_Q(1,0); BAR;
  }

#undef BAR
#undef SB0
#undef VM4

  // ---- epilogue: h = relu(acc + b1); p = h*W2; shfl-reduce; LDS-reduce over wc;
  //      ONE coalesced store per block (no atomics — R5 fix) ----
  float b1v[4];
  float w2v[4][3];
#pragma unroll
  for (int n = 0; n < 4; ++n) {
    int gc = nt * 256 + wc * 64 + n * 16 + laneq;
    b1v[n] = b1[gc];
    w2v[n][0] = W2[gc * 3 + 0];
    w2v[n][1] = W2[gc * 3 + 1];
    w2v[n][2] = W2[gc * 3 + 2];
  }

  float* red = (float*)lds;   // [4 wc][256 rows][3] f32 = 12 KB (K-loop LDS dead)
#pragma unroll
  for (int m = 0; m < 8; ++m) {
#pragma unroll
    for (int q = 0; q < 4; ++q) {
      float p0 = 0.f, p1 = 0.f, p2 = 0.f;
#pragma unroll
      for (int n = 0; n < 4; ++n) {
        float h = acc[m][n][q] + b1v[n];
        h = fmaxf(h, 0.f);
        p0 += h * w2v[n][0];
        p1 += h * w2v[n][1];
        p2 += h * w2v[n][2];
      }
#pragma unroll
      for (int s = 1; s < 16; s <<= 1) {
        p0 += __shfl_xor(p0, s, 64);
        p1 += __shfl_xor(p1, s, 64);
        p2 += __shfl_xor(p2, s, 64);
      }
      if ((lane & 15) == 0) {
        int row = wr * 128 + m * 16 + (lane >> 4) * 4 + q;   // 0..255
        red[(wc * 256 + row) * 3 + 0] = p0;
        red[(wc * 256 + row) * 3 + 1] = p1;
        red[(wc * 256 + row) * 3 + 2] = p2;
      }
    }
  }
  __syncthreads();
  if (tid < 256) {
    float s0 = 0.f, s1 = 0.f, s2 = 0.f;
#pragma unroll
    for (int w = 0; w < 4; ++w) {
      s0 += red[(w * 256 + tid) * 3 + 0];
      s1 += red[(w * 256 + tid) * 3 + 1];
      s2 += red[(w * 256 + tid) * 3 + 2];
    }
    size_t o = ((size_t)nt * 16384 + (size_t)mt * 256 + tid) * 3;
    partials[o + 0] = s0;
    partials[o + 1] = s1;
    partials[o + 2] = s2;
  }
}

// ---------------- finalize: sum partials, log-softmax, gather, logsumexp ----------------
__device__ __forceinline__ float blockReduceSum(float v, float* red, int t) {
#pragma unroll
  for (int s = 32; s >= 1; s >>= 1) v += __shfl_xor(v, s, 64);
  __syncthreads();
  if ((t & 63) == 0) red[t >> 6] = v;
  __syncthreads();
  return red[0] + red[1] + red[2] + red[3];
}

__global__ __launch_bounds__(256) void finalize(
    const float* __restrict__ partials, // [4][16384][3]
    const float* __restrict__ b2,       // [3]
    const int* __restrict__ seq_mask,   // [32][512]
    const int* __restrict__ ans,        // [32][8][512]
    const int* __restrict__ span,       // [32][512]
    const int* __restrict__ isbio,      // [32]
    float* __restrict__ out)            // [32]
{
  int b = blockIdx.x;
  int t = threadIdx.x;
  __shared__ float lp[512][3];
  __shared__ float red[4];
  __shared__ float seq_ll[9];
  __shared__ int preg;

  float b20 = b2[0], b21 = b2[1], b22 = b2[2];
  const int NP = 16384 * 3;

  for (int l = t; l < 512; l += 256) {
    int gi = b * 512 + l;
    float x0 = b20, x1 = b21, x2 = b22;
#pragma unroll
    for (int w = 0; w < 4; ++w) {
      x0 += partials[w * NP + gi * 3 + 0];
      x1 += partials[w * NP + gi * 3 + 1];
      x2 += partials[w * NP + gi * 3 + 2];
    }
    float mx = fmaxf(x0, fmaxf(x1, x2));
    float lse = mx + logf(expf(x0 - mx) + expf(x1 - mx) + expf(x2 - mx));
    float msk = (float)seq_mask[gi];
    lp[l][0] = (x0 - lse) * msk;
    lp[l][1] = (x1 - lse) * msk;
    lp[l][2] = (x2 - lse) * msk;
  }
  __syncthreads();

  // is_pregen = sum(ans * seq_mask) > 0
  float s = 0.f;
  for (int i = t; i < 8 * 512; i += 256) {
    int m = i >> 9, l = i & 511;
    s += (float)(ans[(b * 8 + m) * 512 + l] * seq_mask[b * 512 + l]);
  }
  s = blockReduceSum(s, red, t);
  if (t == 0) preg = (s > 0.f) ? 1 : 0;
  __syncthreads();
  int ip = preg;

  for (int m = 0; m < 9; ++m) {
    float sll = 0.f, sidx = 0.f;
    for (int l = t; l < 512; l += 256) {
      int idx;
      if (m < 8) idx = ans[(b * 8 + m) * 512 + l] * seq_mask[b * 512 + l];
      else       idx = span[b * 512 + l] * (1 - ip);
      sll  += lp[l][idx];
      sidx += (float)idx;
    }
    sll  = blockReduceSum(sll, red, t);
    sidx = blockReduceSum(sidx, red, t);
    if (t == 0) seq_ll[m] = (sidx > 0.f) ? sll : NEGV;
  }

  if (t == 0) {
    float mx = seq_ll[0];
#pragma unroll
    for (int m = 1; m < 9; ++m) mx = fmaxf(mx, seq_ll[m]);
    float sum = 0.f;
#pragma unroll
    for (int m = 0; m < 9; ++m) sum += expf(seq_ll[m] - mx);
    float lml = mx + logf(sum);
    out[b] = isbio[b] ? lml : NEGV;
  }
}

extern "C" void kernel_launch(void* const* d_in, const int* in_sizes, int n_in,
                              void* d_out, int out_size, void* d_ws, size_t ws_size,
                              hipStream_t stream) {
  const float* bert     = (const float*)d_in[0];
  const int*   seq_mask = (const int*)d_in[1];
  // d_in[2] wordpiece_mask: unused
  // d_in[3] answer_as_text_to_disjoint_bios: unused
  const int*   ans      = (const int*)d_in[4];
  const int*   span     = (const int*)d_in[5];
  const int*   isbio    = (const int*)d_in[6];
  const float* W1       = (const float*)d_in[7];
  const float* b1       = (const float*)d_in[8];
  const float* W2       = (const float*)d_in[9];
  const float* b2       = (const float*)d_in[10];
  float* out = (float*)d_out;

  char* ws = (char*)d_ws;
  float* partials     = (float*)ws;                                     // 768 KB, fully written
  unsigned short* Abf = (unsigned short*)(ws + (1 << 20));              // 32 MB
  unsigned short* W1T = (unsigned short*)(ws + (1 << 20) + (size_t)16384 * 1024 * 2); // 2 MB

  cvt_all<<<3072, 256, 0, stream>>>(bert, Abf, W1, W1T);
  gemm_fused<<<256, 512, 0, stream>>>(Abf, W1T, b1, W2, partials);
  finalize<<<32, 256, 0, stream>>>(partials, b2, seq_mask, ans, span, isbio, out);
}

// Round 10
// 74.887 us; speedup vs baseline: 1.1228x; 1.0224x over previous
//
#include <hip/hip_runtime.h>
#include <hip/hip_bf16.h>
#include <cstdint>

#define GLOBAL_AS __attribute__((address_space(1)))
#define LDS_AS    __attribute__((address_space(3)))

typedef float f4v  __attribute__((ext_vector_type(4)));
typedef unsigned short u8s __attribute__((ext_vector_type(8)));

#define NEGV (-1e7f)

__device__ __forceinline__ void gload_lds16(const void* g, void* l) {
  __builtin_amdgcn_global_load_lds((const GLOBAL_AS uint32_t*)g,
                                   (LDS_AS uint32_t*)l, 16, 0, 0);
}

// f32 -> fp8 e4m3 (OCP) single value via the packed-convert instruction
__device__ __forceinline__ unsigned char f2fp8(float x) {
  return (unsigned char)(__builtin_amdgcn_cvt_pk_fp8_f32(x, x, 0, false) & 0xff);
}

// ------- combined: bert f32 -> fp8 (x16 scale)  +  W1 transpose -> fp8 (x128 scale) -------
__global__ __launch_bounds__(256) void cvt_all(const float* __restrict__ bert,
                                               unsigned char* __restrict__ afp8,
                                               const float* __restrict__ w1,
                                               unsigned char* __restrict__ w1t) {
  __shared__ float tile[32][33];
  if (blockIdx.x < 2048) {
    const int n8 = 16384 * 1024 / 8;
    int i = blockIdx.x * 256 + threadIdx.x;
    for (; i < n8; i += 2048 * 256) {
      float4 a = ((const float4*)bert)[2 * i + 0];
      float4 b = ((const float4*)bert)[2 * i + 1];
      int lo = __builtin_amdgcn_cvt_pk_fp8_f32(a.x * 16.f, a.y * 16.f, 0, false);
      lo     = __builtin_amdgcn_cvt_pk_fp8_f32(a.z * 16.f, a.w * 16.f, lo, true);
      int hi = __builtin_amdgcn_cvt_pk_fp8_f32(b.x * 16.f, b.y * 16.f, 0, false);
      hi     = __builtin_amdgcn_cvt_pk_fp8_f32(b.z * 16.f, b.w * 16.f, hi, true);
      ((int2*)afp8)[i] = make_int2(lo, hi);
    }
  } else {
    int bb = blockIdx.x - 2048;
    int bx = bb & 31;   // n-tile
    int by = bb >> 5;   // k-tile
    int tx = threadIdx.x & 31;
    int ty = threadIdx.x >> 5;  // 0..7
#pragma unroll
    for (int j = 0; j < 4; ++j) {
      int kk = ty + j * 8;
      tile[kk][tx] = w1[(size_t)(by * 32 + kk) * 1024 + bx * 32 + tx];
    }
    __syncthreads();
#pragma unroll
    for (int j = 0; j < 4; ++j) {
      int nn = ty + j * 8;
      w1t[(size_t)(bx * 32 + nn) * 1024 + by * 32 + tx] = f2fp8(tile[tx][nn] * 128.f);
    }
  }
}

// ---------------- fused GEMM (fp8): h = relu((A16*W128)/2048 + b1); partial logits ----------
// R10: dtype bf16 -> fp8 e4m3, BK 64 -> 128. Row stride stays 128 B, so the
// ENTIRE verified R9 staging/swizzle/vmcnt machinery is byte-identical:
// 16 KB half-slots, 2 gload_lds/wave/half-slot, pre-swizzled source col
// ((l&7)*16)^((row&7)<<4), VM4 at phases 4&8, dummy slot for overflow stages.
// Reads become ds_read_b64 (8 B frags, k=(lane>>4)*8+j per MFMA layout);
// LDS read-pipe time halves (the R9 wall). MFMA: 16x16x32_fp8_fp8 (i64 ops),
// 32 per cluster (4m x 2n x 4kh). Scales: A x16, W1 x128 -> acc/2048 in epilogue.
// Epilogue: atomic-free per-block coalesced store (R5 fix).
__global__ __launch_bounds__(512, 2) void gemm_fused(
    const unsigned char* __restrict__ Afp8,   // [16384][1024] fp8 (bert*16)
    const unsigned char* __restrict__ Bfp8,   // [1024][1024] fp8 (W1^T * 128)
    const float* __restrict__ b1,
    const float* __restrict__ W2,             // [1024][3] f32
    float* __restrict__ partials)             // [4][16384][3] f32
{
  __shared__ __align__(16) char lds[147456];  // 2 x 64KB tile bufs + 16KB dummy

  // bijective XCD swizzle: 256 wgs, 8 XCDs, 32 per XCD
  int bid = blockIdx.x;
  int wid = (bid & 7) * 32 + (bid >> 3);
  int mt = wid >> 2;   // 0..63
  int nt = wid & 3;    // 0..3

  int tid  = threadIdx.x;
  int lane = tid & 63;
  int wv   = tid >> 6;  // 0..7
  int wr   = wv >> 2;   // wave row (0..1): rows wr*128..+127
  int wc   = wv & 3;    // wave col (0..3): cols wc*64..+63

  int laneq = lane & 15;
  int klo8  = (lane >> 4) * 8;        // byte offset of this lane's 8 k-elems
  int sw    = (laneq & 7) << 4;       // row-derived XOR (16B-granular)

  const size_t arow0 = (size_t)mt * 256;
  const size_t brow0 = (size_t)nt * 256;

  // staging source: row (lane>>3), pre-swizzled byte col (fp8: 1 B/elem)
  int scol = ((lane & 7) * 16) ^ ((lane >> 3) << 4);
  const unsigned char* gA = Afp8 + (arow0 + (lane >> 3)) * 1024 + scol
                                 + (size_t)wv * 16 * 1024;
  const unsigned char* gB = Bfp8 + (brow0 + (lane >> 3)) * 1024 + scol
                                 + (size_t)wv * 16 * 1024;

  f4v acc[8][4];
#pragma unroll
  for (int m = 0; m < 8; ++m)
#pragma unroll
    for (int n = 0; n < 4; ++n)
      acc[m][n] = f4v{0.f, 0.f, 0.f, 0.f};

  long a_frag[4][4];      // [m][kh] 8 fp8 each
  long b_frag[2][2][4];   // [np][n2][kh]

  // stage one 16KB half-slot: 2 x gload_lds per thread (8 rows each). 8 K-tiles.
  auto STAGE = [&](int ts, int isB, int rh) {
    int ok  = ts < 8;
    int tcl = ok ? ts : 7;
    const unsigned char* g = (isB ? gB : gA) + (size_t)rh * 128 * 1024 + tcl * 128;
    int dst = ok ? (((tcl & 1) << 16) | (isB << 15) | (rh << 14) | (wv << 11))
                 : (131072 + (wv << 11));
    gload_lds16(g,            lds + dst);
    gload_lds16(g + 8 * 1024, lds + dst + 1024);
  };

  auto READ_A = [&](int buf, int mq) {
    const char* p = lds + (buf << 16) + (wr << 14) + mq * 8192 + laneq * 128;
#pragma unroll
    for (int m = 0; m < 4; ++m)
#pragma unroll
      for (int kh = 0; kh < 4; ++kh)
        a_frag[m][kh] = *(const long*)(p + m * 2048 + ((kh * 32 + klo8) ^ sw));
  };
  auto READ_B = [&](int buf, int np) {
    const char* p = lds + (buf << 16) + 32768 + ((wc >> 1) << 14)
                        + ((wc & 1) * 64 + laneq) * 128 + np * 4096;
#pragma unroll
    for (int n2 = 0; n2 < 2; ++n2)
#pragma unroll
      for (int kh = 0; kh < 4; ++kh)
        b_frag[np][n2][kh] = *(const long*)(p + n2 * 2048 + ((kh * 32 + klo8) ^ sw));
  };
  auto MFMA_Q = [&](int mq, int np) {
    __builtin_amdgcn_s_setprio(1);
#pragma unroll
    for (int m = 0; m < 4; ++m)
#pragma unroll
      for (int n2 = 0; n2 < 2; ++n2)
#pragma unroll
        for (int kh = 0; kh < 4; ++kh)
          acc[mq*4+m][np*2+n2] = __builtin_amdgcn_mfma_f32_16x16x32_fp8_fp8(
              a_frag[m][kh], b_frag[np][n2][kh], acc[mq*4+m][np*2+n2], 0, 0, 0);
    __builtin_amdgcn_s_setprio(0);
  };

#define BAR  __builtin_amdgcn_s_barrier()
#define SB0  __builtin_amdgcn_sched_barrier(0)
#define VM4  asm volatile("s_waitcnt vmcnt(4)" ::: "memory")

  // prologue: tile0 all 4 half-slots + tile1 {B,h0},{A,h0}; drain tile0, keep 2 in flight
  STAGE(0,1,0); STAGE(0,0,0); STAGE(0,0,1); STAGE(0,1,1);
  STAGE(1,1,0); STAGE(1,0,0);
  VM4; BAR; SB0;

  for (int i = 0; i < 4; ++i) {
    int T = 2 * i;
    // ---- tile T (buf 0) ----
    READ_A(0,0); READ_B(0,0); STAGE(T+1,0,1);
    BAR; SB0; MFMA_Q(0,0); BAR;
    READ_B(0,1);             STAGE(T+1,1,1);
    BAR; SB0; MFMA_Q(0,1); BAR;
    READ_A(0,1);             STAGE(T+2,1,0);
    BAR; SB0; MFMA_Q(1,1); BAR;
                             STAGE(T+2,0,0);
    VM4;
    BAR; SB0; MFMA_Q(1,0); BAR;
    // ---- tile T+1 (buf 1) ----
    READ_A(1,0); READ_B(1,0); STAGE(T+2,0,1);
    BAR; SB0; MFMA_Q(0,0); BAR;
    READ_B(1,1);             STAGE(T+2,1,1);
    BAR; SB0; MFMA_Q(0,1); BAR;
    READ_A(1,1);             STAGE(T+3,1,0);
    BAR; SB0; MFMA_Q(1,1); BAR;
                             STAGE(T+3,0,0);
    VM4;
    BAR; SB0; MFMA_Q(1,0); BAR;
  }

#undef BAR
#undef SB0
#undef VM4

  // ---- epilogue: h = relu(acc/2048 + b1); p = h*W2; shfl-reduce; LDS-reduce; store ----
  const float DS = 1.0f / 2048.0f;   // undo A x16, W1 x128
  float b1v[4];
  float w2v[4][3];
#pragma unroll
  for (int n = 0; n < 4; ++n) {
    int gc = nt * 256 + wc * 64 + n * 16 + laneq;
    b1v[n] = b1[gc];
    w2v[n][0] = W2[gc * 3 + 0];
    w2v[n][1] = W2[gc * 3 + 1];
    w2v[n][2] = W2[gc * 3 + 2];
  }

  float* red = (float*)lds;   // [4 wc][256 rows][3] f32 = 12 KB (K-loop LDS dead)
#pragma unroll
  for (int m = 0; m < 8; ++m) {
#pragma unroll
    for (int q = 0; q < 4; ++q) {
      float p0 = 0.f, p1 = 0.f, p2 = 0.f;
#pragma unroll
      for (int n = 0; n < 4; ++n) {
        float h = acc[m][n][q] * DS + b1v[n];
        h = fmaxf(h, 0.f);
        p0 += h * w2v[n][0];
        p1 += h * w2v[n][1];
        p2 += h * w2v[n][2];
      }
#pragma unroll
      for (int s = 1; s < 16; s <<= 1) {
        p0 += __shfl_xor(p0, s, 64);
        p1 += __shfl_xor(p1, s, 64);
        p2 += __shfl_xor(p2, s, 64);
      }
      if ((lane & 15) == 0) {
        int row = wr * 128 + m * 16 + (lane >> 4) * 4 + q;   // 0..255
        red[(wc * 256 + row) * 3 + 0] = p0;
        red[(wc * 256 + row) * 3 + 1] = p1;
        red[(wc * 256 + row) * 3 + 2] = p2;
      }
    }
  }
  __syncthreads();
  if (tid < 256) {
    float s0 = 0.f, s1 = 0.f, s2 = 0.f;
#pragma unroll
    for (int w = 0; w < 4; ++w) {
      s0 += red[(w * 256 + tid) * 3 + 0];
      s1 += red[(w * 256 + tid) * 3 + 1];
      s2 += red[(w * 256 + tid) * 3 + 2];
    }
    size_t o = ((size_t)nt * 16384 + (size_t)mt * 256 + tid) * 3;
    partials[o + 0] = s0;
    partials[o + 1] = s1;
    partials[o + 2] = s2;
  }
}

// ---------------- finalize: sum partials, log-softmax, gather, logsumexp ----------------
__device__ __forceinline__ float blockReduceSum(float v, float* red, int t) {
#pragma unroll
  for (int s = 32; s >= 1; s >>= 1) v += __shfl_xor(v, s, 64);
  __syncthreads();
  if ((t & 63) == 0) red[t >> 6] = v;
  __syncthreads();
  return red[0] + red[1] + red[2] + red[3];
}

__global__ __launch_bounds__(256) void finalize(
    const float* __restrict__ partials, // [4][16384][3]
    const float* __restrict__ b2,       // [3]
    const int* __restrict__ seq_mask,   // [32][512]
    const int* __restrict__ ans,        // [32][8][512]
    const int* __restrict__ span,       // [32][512]
    const int* __restrict__ isbio,      // [32]
    float* __restrict__ out)            // [32]
{
  int b = blockIdx.x;
  int t = threadIdx.x;
  __shared__ float lp[512][3];
  __shared__ float red[4];
  __shared__ float seq_ll[9];
  __shared__ int preg;

  float b20 = b2[0], b21 = b2[1], b22 = b2[2];
  const int NP = 16384 * 3;

  for (int l = t; l < 512; l += 256) {
    int gi = b * 512 + l;
    float x0 = b20, x1 = b21, x2 = b22;
#pragma unroll
    for (int w = 0; w < 4; ++w) {
      x0 += partials[w * NP + gi * 3 + 0];
      x1 += partials[w * NP + gi * 3 + 1];
      x2 += partials[w * NP + gi * 3 + 2];
    }
    float mx = fmaxf(x0, fmaxf(x1, x2));
    float lse = mx + logf(expf(x0 - mx) + expf(x1 - mx) + expf(x2 - mx));
    float msk = (float)seq_mask[gi];
    lp[l][0] = (x0 - lse) * msk;
    lp[l][1] = (x1 - lse) * msk;
    lp[l][2] = (x2 - lse) * msk;
  }
  __syncthreads();

  // is_pregen = sum(ans * seq_mask) > 0
  float s = 0.f;
  for (int i = t; i < 8 * 512; i += 256) {
    int m = i >> 9, l = i & 511;
    s += (float)(ans[(b * 8 + m) * 512 + l] * seq_mask[b * 512 + l]);
  }
  s = blockReduceSum(s, red, t);
  if (t == 0) preg = (s > 0.f) ? 1 : 0;
  __syncthreads();
  int ip = preg;

  for (int m = 0; m < 9; ++m) {
    float sll = 0.f, sidx = 0.f;
    for (int l = t; l < 512; l += 256) {
      int idx;
      if (m < 8) idx = ans[(b * 8 + m) * 512 + l] * seq_mask[b * 512 + l];
      else       idx = span[b * 512 + l] * (1 - ip);
      sll  += lp[l][idx];
      sidx += (float)idx;
    }
    sll  = blockReduceSum(sll, red, t);
    sidx = blockReduceSum(sidx, red, t);
    if (t == 0) seq_ll[m] = (sidx > 0.f) ? sll : NEGV;
  }

  if (t == 0) {
    float mx = seq_ll[0];
#pragma unroll
    for (int m = 1; m < 9; ++m) mx = fmaxf(mx, seq_ll[m]);
    float sum = 0.f;
#pragma unroll
    for (int m = 0; m < 9; ++m) sum += expf(seq_ll[m] - mx);
    float lml = mx + logf(sum);
    out[b] = isbio[b] ? lml : NEGV;
  }
}

extern "C" void kernel_launch(void* const* d_in, const int* in_sizes, int n_in,
                              void* d_out, int out_size, void* d_ws, size_t ws_size,
                              hipStream_t stream) {
  const float* bert     = (const float*)d_in[0];
  const int*   seq_mask = (const int*)d_in[1];
  // d_in[2] wordpiece_mask: unused
  // d_in[3] answer_as_text_to_disjoint_bios: unused
  const int*   ans      = (const int*)d_in[4];
  const int*   span     = (const int*)d_in[5];
  const int*   isbio    = (const int*)d_in[6];
  const float* W1       = (const float*)d_in[7];
  const float* b1       = (const float*)d_in[8];
  const float* W2       = (const float*)d_in[9];
  const float* b2       = (const float*)d_in[10];
  float* out = (float*)d_out;

  char* ws = (char*)d_ws;
  float* partials      = (float*)ws;                                    // 768 KB, fully written
  unsigned char* Afp8  = (unsigned char*)(ws + (1 << 20));              // 16 MB
  unsigned char* W1T8  = (unsigned char*)(ws + (1 << 20) + (size_t)16384 * 1024); // 1 MB

  cvt_all<<<3072, 256, 0, stream>>>(bert, Afp8, W1, W1T8);
  gemm_fused<<<256, 512, 0, stream>>>(Afp8, W1T8, b1, W2, partials);
  finalize<<<32, 256, 0, stream>>>(partials, b2, seq_mask, ans, span, isbio, out);
}